// Round 6
// baseline (690.788 us; speedup 1.0000x reference)
//
#include <hip/hip_runtime.h>
#include <hip/hip_bf16.h>

#define N_NODES 100000
#define NEDGE   600000
#define SCAN_B  1024
#define NBLK    98            // ceil(N_NODES / SCAN_B)
#define NCHUNK  293           // ceil(NEDGE / 2048)
#define XRANGE  12500         // N_NODES / 8 (per-XCD dst range)

typedef __attribute__((ext_vector_type(8))) short bf16x8;
typedef __attribute__((ext_vector_type(4))) short s16x4;
typedef __attribute__((ext_vector_type(4))) float f32x4;
typedef __attribute__((ext_vector_type(2))) unsigned u32x2;

__device__ __forceinline__ short f2bf(float f) {
  union { float f; unsigned u; } x; x.f = f;
  unsigned r = x.u + 0x7FFFu + ((x.u >> 16) & 1u);
  return (short)(r >> 16);
}

// XCD-localized degree count: class g = bid&7 owns dst range [g*XRANGE, ...).
// All atomics for a cnt line issue from one XCD -> line stays in that L2.
__global__ __launch_bounds__(256) void count_deg_k(const int* __restrict__ didx,
                                                   int* __restrict__ cnt) {
  int b = blockIdx.x;
  int g = b & 7, c = b >> 3;
  int r = blockIdx.y;
  int lo = g * XRANGE, hi = lo + XRANGE;
  const int* dd = didx + (size_t)r * NEDGE;
  int* cn = cnt + r * N_NODES;
  int base = c * 2048 + threadIdx.x;
#pragma unroll
  for (int j = 0; j < 8; ++j) {
    int e = base + j * 256;
    if (e < NEDGE) {
      int d = dd[e];
      if (d >= lo && d < hi) atomicAdd(&cn[d], 1);
    }
  }
}

// Phase 1: per-block chunk sums. grid (NBLK, 4), 256 thr, 4 elems/thr.
__global__ __launch_bounds__(256) void scan1_k(const int* __restrict__ cnt,
                                               int* __restrict__ bsum) {
  __shared__ int lds[256];
  int b = blockIdx.x, r = blockIdx.y, t = threadIdx.x;
  int i0 = b * SCAN_B + t * 4;
  int s = 0;
#pragma unroll
  for (int j = 0; j < 4; ++j)
    if (i0 + j < N_NODES) s += cnt[r * N_NODES + i0 + j];
  lds[t] = s;
  __syncthreads();
  for (int st = 128; st > 0; st >>= 1) {
    if (t < st) lds[t] += lds[t + st];
    __syncthreads();
  }
  if (t == 0) bsum[r * NBLK + b] = lds[0];
}

// Phase 2: exclusive scan of the NBLK block sums per relation. 1 block, 128 thr.
__global__ __launch_bounds__(128) void scan2_k(int* __restrict__ bsum) {
  __shared__ int buf[128];
  int t = threadIdx.x;
  for (int r = 0; r < 4; ++r) {
    int v = (t < NBLK) ? bsum[r * NBLK + t] : 0;
    buf[t] = v;
    __syncthreads();
    for (int st = 1; st < 128; st <<= 1) {
      int x = (t >= st) ? buf[t - st] : 0;
      __syncthreads();
      buf[t] += x;
      __syncthreads();
    }
    if (t < NBLK) bsum[r * NBLK + t] = buf[t] - v;   // exclusive
    __syncthreads();
  }
}

// Phase 3: local exclusive scan + block base -> off. grid (NBLK, 4), 256 thr.
__global__ __launch_bounds__(256) void scan3_k(const int* __restrict__ cnt,
                                               const int* __restrict__ bsum,
                                               int* __restrict__ off) {
  __shared__ int lds[256];
  int b = blockIdx.x, r = blockIdx.y, t = threadIdx.x;
  int i0 = b * SCAN_B + t * 4;
  int c[4] = {0, 0, 0, 0};
#pragma unroll
  for (int j = 0; j < 4; ++j)
    if (i0 + j < N_NODES) c[j] = cnt[r * N_NODES + i0 + j];
  int s = c[0] + c[1] + c[2] + c[3];
  lds[t] = s;
  __syncthreads();
  for (int st = 1; st < 256; st <<= 1) {
    int x = (t >= st) ? lds[t - st] : 0;
    __syncthreads();
    lds[t] += x;
    __syncthreads();
  }
  int run = bsum[r * NBLK + b] + lds[t] - s;
  int* o = off + r * (N_NODES + 1);
#pragma unroll
  for (int j = 0; j < 4; ++j) {
    if (i0 + j < N_NODES) { o[i0 + j] = run; run += c[j]; }
  }
  if (b == 0 && t == 0) o[N_NODES] = NEDGE;
}

// XCD-localized CSR fill with localized cursor atomics. Class g = bid&7 owns
// dst range; cursor/csr lines for that range only ever touched by one XCD.
__global__ __launch_bounds__(256) void fill_csr_k(const int* __restrict__ sidx,
                                                  const int* __restrict__ didx,
                                                  const int* __restrict__ off,
                                                  int* __restrict__ cursor,
                                                  int* __restrict__ csr) {
  int b = blockIdx.x;
  int g = b & 7, c = b >> 3;
  int r = blockIdx.y;
  int lo = g * XRANGE, hi = lo + XRANGE;
  const int* dd = didx + (size_t)r * NEDGE;
  const int* ss = sidx + (size_t)r * NEDGE;
  const int* of = off + r * (N_NODES + 1);
  int* cu = cursor + r * N_NODES;
  int* cs = csr + (size_t)r * NEDGE;
  int base = c * 2048 + threadIdx.x;
#pragma unroll
  for (int j = 0; j < 8; ++j) {
    int e = base + j * 256;
    if (e < NEDGE) {
      int d = dd[e];
      if (d >= lo && d < hi) {
        int pos = of[d] + atomicAdd(&cu[d], 1);
        cs[pos] = ss[e];
      }
    }
  }
}

// f32 -> packed bf16 (2 per u32); each thread converts 8 floats.
__global__ __launch_bounds__(256) void cvt_bf16_k(const float* __restrict__ x,
                                                  unsigned* __restrict__ o) {
  int i = blockIdx.x * 256 + threadIdx.x;     // i < N_NODES*16
  if (i >= N_NODES * 16) return;
  f32x4 v0 = ((const f32x4*)x)[i * 2];
  f32x4 v1 = ((const f32x4*)x)[i * 2 + 1];
  unsigned r0 = (unsigned)(unsigned short)f2bf(v0[0]) |
                ((unsigned)(unsigned short)f2bf(v0[1]) << 16);
  unsigned r1 = (unsigned)(unsigned short)f2bf(v0[2]) |
                ((unsigned)(unsigned short)f2bf(v0[3]) << 16);
  unsigned r2 = (unsigned)(unsigned short)f2bf(v1[0]) |
                ((unsigned)(unsigned short)f2bf(v1[1]) << 16);
  unsigned r3 = (unsigned)(unsigned short)f2bf(v1[2]) |
                ((unsigned)(unsigned short)f2bf(v1[3]) << 16);
  typedef __attribute__((ext_vector_type(4))) unsigned u32x4;
  ((u32x4*)o)[i] = (u32x4){r0, r1, r2, r3};
}

// Pack combined weights into MFMA B-fragment-linear layout.
__global__ __launch_bounds__(256) void prep_w_k(const float* __restrict__ Ws1,
                                                const float* __restrict__ Wn1,
                                                const float* __restrict__ Ws2,
                                                const float* __restrict__ Wn2,
                                                short* __restrict__ WTp) {
  int tid = blockIdx.x * 256 + threadIdx.x;  // 0..98303
  int lane = tid & 63;
  int n0 = (tid >> 6) & 7;
  int idx3 = tid >> 9;
  int k0 = idx3 % 12;
  int lt = idx3 / 12;
  int l = lt >> 1, t = lt & 1;
  const float* Wself  = l ? Ws2 : Ws1;
  const float* Wneigh = l ? Wn2 : Wn1;
  int rA = t ? 0 : 1, rB = t ? 3 : 2;
  int n = n0 * 16 + (lane & 15);
  int kbase = k0 * 32 + (lane >> 4) * 8;
  short out[8];
#pragma unroll
  for (int j = 0; j < 8; ++j) {
    int k = kbase + j;
    int kk = k & 127, blk = k >> 7;
    float v;
    if (blk == 0)      v = Wself[rA * 16384 + kk * 128 + n] + Wself[rB * 16384 + kk * 128 + n];
    else if (blk == 1) v = Wneigh[rA * 16384 + kk * 128 + n];
    else               v = Wneigh[rB * 16384 + kk * 128 + n];
    out[j] = f2bf(v);
  }
  s16x4* dst = (s16x4*)&WTp[tid * 8];
  dst[0] = *(s16x4*)&out[0];
  dst[1] = *(s16x4*)&out[4];
}

__global__ __launch_bounds__(256) void prep_b_k(const float* __restrict__ b1,
                                                const float* __restrict__ b2,
                                                float* __restrict__ biasc) {
  int tid = blockIdx.x * 256 + threadIdx.x;
  if (tid >= 512) return;
  int l = tid >> 8, t = (tid >> 7) & 1, c = tid & 127;
  const float* b = l ? b2 : b1;
  int rA = t ? 0 : 1, rB = t ? 3 : 2;
  biasc[tid] = b[rA * 128 + c] + b[rB * 128 + c];
}

// One wave per (node, relation). Lane loads u32x2 (8B), 32 lanes cover a row,
// so each load instr fetches TWO edge rows: 8 edges in flight per iteration.
__global__ __launch_bounds__(256) void gather_mean_k(const unsigned* __restrict__ src,
    const int* __restrict__ csrA, const int* __restrict__ offA,
    const int* __restrict__ csrB, const int* __restrict__ offB,
    unsigned* __restrict__ meanA, unsigned* __restrict__ meanB) {
  int wv = __builtin_amdgcn_readfirstlane(threadIdx.x >> 6);
  int wid = blockIdx.x * 4 + wv;
  int lane = threadIdx.x & 63;
  int n = wid >> 1, rel = wid & 1;
  if (n >= N_NODES) return;
  const int* csr = rel ? csrB : csrA;
  const int* off = rel ? offB : offA;
  unsigned* mean = rel ? meanB : meanA;
  int p0 = off[n], p1 = off[n + 1];
  int deg = p1 - p0;
  int half = lane >> 5;          // which edge of each pair this lane serves
  int colu = lane & 31;          // u32-pair column: u32s {2*colu, 2*colu+1}
  float a0 = 0.f, a1 = 0.f, a2 = 0.f, a3 = 0.f;
  for (int p = p0; p < p1; p += 8) {
    int idx[4];
#pragma unroll
    for (int j = 0; j < 4; ++j) {
      int pc = p + j * 2 + half;
      idx[j] = csr[pc < p1 ? pc : p0];
    }
    u32x2 u[4];
#pragma unroll
    for (int j = 0; j < 4; ++j)
      u[j] = *(const u32x2*)(src + (size_t)idx[j] * 64 + colu * 2);
#pragma unroll
    for (int j = 0; j < 4; ++j) {
      if (p + j * 2 + half < p1) {
        union { unsigned q; float f; } x;
        x.q = u[j][0] << 16;         a0 += x.f;
        x.q = u[j][0] & 0xffff0000u; a1 += x.f;
        x.q = u[j][1] << 16;         a2 += x.f;
        x.q = u[j][1] & 0xffff0000u; a3 += x.f;
      }
    }
  }
  // fold the two halves: lane l (<32) += lane l+32 (same columns)
  a0 += __shfl_down(a0, 32);
  a1 += __shfl_down(a1, 32);
  a2 += __shfl_down(a2, 32);
  a3 += __shfl_down(a3, 32);
  if (half == 0) {
    float inv = 1.0f / (float)(deg > 1 ? deg : 1);
    unsigned w0 = (unsigned)(unsigned short)f2bf(a0 * inv) |
                  ((unsigned)(unsigned short)f2bf(a1 * inv) << 16);
    unsigned w1 = (unsigned)(unsigned short)f2bf(a2 * inv) |
                  ((unsigned)(unsigned short)f2bf(a3 * inv) << 16);
    *(u32x2*)(mean + (size_t)n * 64 + colu * 2) = (u32x2){w0, w1};
  }
}

// C[M=100000 x 128] = [self | meanA | meanB] (K=384, all bf16) @ W (in LDS)
template<int OUT_RELU_BF16>
__global__ __launch_bounds__(256) void gemm_k(const short* __restrict__ selfp,
    const short* __restrict__ meanA, const short* __restrict__ meanB,
    const short* __restrict__ WTp, const float* __restrict__ biasc,
    void* __restrict__ outp) {
  __shared__ short Wlds[6 * 8 * 512];   // 48KB
  int tid = threadIdx.x;
  int lane = tid & 63, wave = tid >> 6;
  int rowbase = blockIdx.x * 128 + wave * 32;
  int r0 = rowbase + (lane & 15), r1 = r0 + 16;
  int rc0 = r0 < N_NODES ? r0 : N_NODES - 1;
  int rc1 = r1 < N_NODES ? r1 : N_NODES - 1;
  int kg = lane >> 4;
  f32x4 acc[2][8] = {};
  for (int half = 0; half < 2; ++half) {
    __syncthreads();
    const f32x4* s = (const f32x4*)WTp + half * 3072;
    f32x4* dst = (f32x4*)Wlds;
#pragma unroll
    for (int i = 0; i < 12; ++i) dst[tid + i * 256] = s[tid + i * 256];
    __syncthreads();
    for (int k0h = 0; k0h < 6; ++k0h) {
      int k0 = half * 6 + k0h;
      int kin = (k0 & 3) * 32 + kg * 8;
      const short* mp = (k0 < 4) ? selfp : ((k0 < 8) ? meanA : meanB);
      bf16x8 a0 = *(const bf16x8*)(mp + (size_t)rc0 * 128 + kin);
      bf16x8 a1 = *(const bf16x8*)(mp + (size_t)rc1 * 128 + kin);
      const short* wb = &Wlds[k0h * 4096 + lane * 8];
#pragma unroll
      for (int n0 = 0; n0 < 8; ++n0) {
        bf16x8 b = *(const bf16x8*)(wb + n0 * 512);
        acc[0][n0] = __builtin_amdgcn_mfma_f32_16x16x32_bf16(a0, b, acc[0][n0], 0, 0, 0);
        acc[1][n0] = __builtin_amdgcn_mfma_f32_16x16x32_bf16(a1, b, acc[1][n0], 0, 0, 0);
      }
    }
  }
  int colb = lane & 15, rloc = kg * 4;
#pragma unroll
  for (int mt = 0; mt < 2; ++mt) {
    int rb = rowbase + mt * 16 + rloc;
#pragma unroll
    for (int n0 = 0; n0 < 8; ++n0) {
      int cc = n0 * 16 + colb;
      float bv = biasc[cc];
#pragma unroll
      for (int j = 0; j < 4; ++j) {
        int rr = rb + j;
        if (rr < N_NODES) {
          float v = acc[mt][n0][j] + bv;
          if (OUT_RELU_BF16) {
            ((short*)outp)[(size_t)rr * 128 + cc] = f2bf(v > 0.f ? v : 0.f);
          } else {
            ((float*)outp)[(size_t)rr * 128 + cc] = v;
          }
        }
      }
    }
  }
}

extern "C" void kernel_launch(void* const* d_in, const int* in_sizes, int n_in,
                              void* d_out, int out_size, void* d_ws, size_t ws_size,
                              hipStream_t stream) {
  (void)in_sizes; (void)n_in; (void)out_size; (void)ws_size;
  const float* xq  = (const float*)d_in[0];
  const float* xp  = (const float*)d_in[1];
  const int*   src = (const int*)d_in[2];
  const int*   dst = (const int*)d_in[3];
  const float* Ws1 = (const float*)d_in[4];
  const float* Wn1 = (const float*)d_in[5];
  const float* b1  = (const float*)d_in[6];
  const float* Ws2 = (const float*)d_in[7];
  const float* Wn2 = (const float*)d_in[8];
  const float* b2  = (const float*)d_in[9];

  char* w = (char*)d_ws;
  int*   cnt    = (int*)w;      w += (size_t)4 * N_NODES * 4;
  int*   cursor = (int*)w;      w += (size_t)4 * N_NODES * 4;
  int*   off    = (int*)w;      w += (size_t)4 * (N_NODES + 1) * 4;
  int*   csr    = (int*)w;      w += (size_t)4 * NEDGE * 4;
  short* meanA  = (short*)w;    w += (size_t)N_NODES * 128 * 2;
  short* meanB  = (short*)w;    w += (size_t)N_NODES * 128 * 2;
  short* h1q    = (short*)w;    w += (size_t)N_NODES * 128 * 2;
  short* h1p    = (short*)w;    w += (size_t)N_NODES * 128 * 2;
  short* xqb    = (short*)w;    w += (size_t)N_NODES * 128 * 2;
  short* xpb    = (short*)w;    w += (size_t)N_NODES * 128 * 2;
  short* WTp    = (short*)w;    w += (size_t)4 * 49152 * 2;
  float* biasc  = (float*)w;    w += 512 * 4;
  int*   bsum   = (int*)w;      w += 4 * 128 * 4;

  dim3 b256(256);
  const int ggrid = (N_NODES + 127) / 128;        // 782
  const int wgrid = (2 * N_NODES + 3) / 4;        // 50000 (wave per node,rel)
  const int cgrid = (N_NODES * 16 + 255) / 256;   // 6250
  const int NP1 = N_NODES + 1;

  // --- CSR build (dst_idx fixed -> once per call, reused by both layers)
  hipMemsetAsync(cnt, 0, (size_t)8 * N_NODES * 4, stream);   // cnt + cursor
  count_deg_k<<<dim3(NCHUNK * 8, 4), b256, 0, stream>>>(dst, cnt);
  scan1_k<<<dim3(NBLK, 4), b256, 0, stream>>>(cnt, bsum);
  scan2_k<<<dim3(1), dim3(128), 0, stream>>>(bsum);
  scan3_k<<<dim3(NBLK, 4), b256, 0, stream>>>(cnt, bsum, off);
  fill_csr_k<<<dim3(NCHUNK * 8, 4), b256, 0, stream>>>(src, dst, off, cursor, csr);
  prep_w_k<<<dim3(384), b256, 0, stream>>>(Ws1, Wn1, Ws2, Wn2, WTp);
  prep_b_k<<<dim3(2), b256, 0, stream>>>(b1, b2, biasc);
  cvt_bf16_k<<<dim3(cgrid), b256, 0, stream>>>(xq, (unsigned*)xqb);
  cvt_bf16_k<<<dim3(cgrid), b256, 0, stream>>>(xp, (unsigned*)xpb);

  // ---- Layer 1, type 0 (Query): rels 1,2 ; src nodes = x_product (bf16)
  gather_mean_k<<<wgrid, b256, 0, stream>>>((const unsigned*)xpb,
      csr + 1 * NEDGE, off + 1 * NP1, csr + 2 * NEDGE, off + 2 * NP1,
      (unsigned*)meanA, (unsigned*)meanB);
  gemm_k<1><<<ggrid, b256, 0, stream>>>(xqb, meanA, meanB,
      WTp + 0 * 49152, biasc + 0, h1q);

  // ---- Layer 1, type 1 (Product): rels 0,3 ; src = x_query (bf16)
  gather_mean_k<<<wgrid, b256, 0, stream>>>((const unsigned*)xqb,
      csr + 0 * NEDGE, off + 0 * NP1, csr + 3 * NEDGE, off + 3 * NP1,
      (unsigned*)meanA, (unsigned*)meanB);
  gemm_k<1><<<ggrid, b256, 0, stream>>>(xpb, meanA, meanB,
      WTp + 1 * 49152, biasc + 128, h1p);

  // ---- Layer 2, type 0 (Query): rels 1,2 ; src = h1p (bf16)
  gather_mean_k<<<wgrid, b256, 0, stream>>>((const unsigned*)h1p,
      csr + 1 * NEDGE, off + 1 * NP1, csr + 2 * NEDGE, off + 2 * NP1,
      (unsigned*)meanA, (unsigned*)meanB);
  gemm_k<0><<<ggrid, b256, 0, stream>>>(h1q, meanA, meanB,
      WTp + 2 * 49152, biasc + 256, (float*)d_out);

  // ---- Layer 2, type 1 (Product): rels 0,3 ; src = h1q (bf16)
  gather_mean_k<<<wgrid, b256, 0, stream>>>((const unsigned*)h1q,
      csr + 0 * NEDGE, off + 0 * NP1, csr + 3 * NEDGE, off + 3 * NP1,
      (unsigned*)meanA, (unsigned*)meanB);
  gemm_k<0><<<ggrid, b256, 0, stream>>>(h1p, meanA, meanB,
      WTp + 3 * 49152, biasc + 384, (float*)d_out + (size_t)N_NODES * 128);
}